// Round 9
// baseline (2680.871 us; speedup 1.0000x reference)
//
#include <hip/hip_runtime.h>
#include <hip/hip_bf16.h>

#define TPB 256
constexpr int B_ = 256, S_ = 512, D_ = 512, Q_ = 256, NM_ = 512;
constexpr int NB = 64, NT = 8;

typedef _Float16 f16x8 __attribute__((ext_vector_type(8)));
typedef float f32x4 __attribute__((ext_vector_type(4)));

__device__ __forceinline__ int pidx(int j, int a){ return j*(15-j)/2 + (a-j-1); } // j<a, 28 tiles

// XCD-co-locating decode: x=bid&7 -> XCD; per XCD: tasks fastest, then cls, then group.
__device__ __forceinline__ void decode_mt(int bid, int W, int& m, int& t){
  int x = bid & 7, r = bid >> 3;
  t = r % W; int u = r / W;
  m = (((u >> 1)*8 + x) << 1) | (u & 1);
}

// direct row-major 64x64 stage into pitch-68 LDS (256 threads)
__device__ __forceinline__ void stage_D(const float* __restrict__ src, size_t ld,
                                        float (*dst)[68], int t)
{
  int r = t >> 2, seg = (t & 3) * 16;
  const float4* s4 = (const float4*)(src + (size_t)r*ld + seg);
  #pragma unroll
  for (int i=0;i<4;i++) *((float4*)&dst[r][seg + i*4]) = s4[i];
}

// acc[u][v] += sum_kk Aop[kk][tr*4+u] * Bop[kk][tc*4+v]
__device__ __forceinline__ void mm_acc68(const float (*Aop)[68], const float (*Bop)[68],
                                         float acc[4][4], int tr, int tc)
{
  for (int kk=0;kk<64;kk++){
    float4 av = *((const float4*)&Aop[kk][tr*4]);
    float4 bv = *((const float4*)&Bop[kk][tc*4]);
    float a[4]={av.x,av.y,av.z,av.w}, b2[4]={bv.x,bv.y,bv.z,bv.w};
    #pragma unroll
    for (int u=0;u<4;u++)
      #pragma unroll
      for (int v=0;v<4;v++) acc[u][v] = fmaf(a[u], b2[v], acc[u][v]);
  }
}

// ---------------- stats: counts, means, pos bitmask (1024 thr, 4-way s-split) ----------------
__global__ __launch_bounds__(1024) void k_stats(const float* __restrict__ X,
                                                const int* __restrict__ labels,
                                                const int* __restrict__ slen,
                                                float* __restrict__ mu,
                                                float* __restrict__ cnt,
                                                unsigned int* __restrict__ wpbits)
{
  int b = blockIdx.x, t = threadIdx.x;
  int td = t & 255, sg = t >> 8;
  __shared__ int lab[S_];
  __shared__ float red[1024];
  __shared__ float part[4][256][4];
  int L = slen[b];
  if (t < S_) {
    int lb = labels[b*S_ + t];
    lab[t] = (t < L) ? lb : -1;
  }
  __syncthreads();
  if (t < 16) {
    unsigned int wword = 0;
    for (int i2 = 0; i2 < 32; i2++) if (lab[t*32 + i2] == 1) wword |= (1u << i2);
    wpbits[b*16 + t] = wword;
  }
  red[t] = (t < S_) ? ((lab[t]==1) ? 1.f : 0.f) : 0.f;
  __syncthreads();
  for (int o=512;o>0;o>>=1){ if(t<o) red[t]+=red[t+o]; __syncthreads(); }
  float cp = red[0]; __syncthreads();
  red[t] = (t < S_) ? ((lab[t]==0) ? 1.f : 0.f) : 0.f;
  __syncthreads();
  for (int o=512;o>0;o>>=1){ if(t<o) red[t]+=red[t+o]; __syncthreads(); }
  float cn = red[0];
  if (t==0){ cnt[b*2+0]=cn; cnt[b*2+1]=cp; }
  float sp0=0,sp1=0,sn0=0,sn1=0;
  const float* Xb = X + (size_t)b*S_*D_;
  for (int s=sg*128; s<sg*128+128; s++){
    int e = lab[s];
    if (e < 0) continue;
    float x0 = Xb[(size_t)s*D_ + td];
    float x1 = Xb[(size_t)s*D_ + td + 256];
    if (e==1){ sp0+=x0; sp1+=x1; } else { sn0+=x0; sn1+=x1; }
  }
  part[sg][td][0]=sn0; part[sg][td][1]=sn1; part[sg][td][2]=sp0; part[sg][td][3]=sp1;
  __syncthreads();
  if (sg == 0){
    float a0=0,a1=0,a2=0,a3=0;
    #pragma unroll
    for (int g=0;g<4;g++){ a0+=part[g][td][0]; a1+=part[g][td][1]; a2+=part[g][td][2]; a3+=part[g][td][3]; }
    float stv = (float)L;
    float* mb = mu + (size_t)b*3*D_;
    mb[0*D_ + td] = a0/cn;      mb[0*D_ + td+256] = a1/cn;
    mb[1*D_ + td] = a2/cp;      mb[1*D_ + td+256] = a3/cp;
    mb[2*D_ + td] = (a0+a2)/stv; mb[2*D_ + td+256] = (a1+a3)/stv;
  }
}

// ---------------- prep: transpose X -> f16 hi/lo [B][D][S], valid-masked ----------------
__global__ __launch_bounds__(TPB) void k_prep(const float* __restrict__ X,
                                              const int* __restrict__ slen,
                                              unsigned short* __restrict__ Xvh,
                                              unsigned short* __restrict__ Xvl)
{
  int b = blockIdx.y, z = blockIdx.x;
  int d0 = (z>>3)*64, s0 = (z&7)*64;
  int t = threadIdx.x;
  __shared__ float Tl[64][65];
  const float* src = X + ((size_t)b*S_ + s0)*D_ + d0;
  { int r = t>>2, seg = (t&3)*16;
    const float4* s4 = (const float4*)(src + (size_t)r*D_ + seg);
    #pragma unroll
    for (int i=0;i<4;i++){ float4 v = s4[i];
      Tl[seg+i*4+0][r]=v.x; Tl[seg+i*4+1][r]=v.y; Tl[seg+i*4+2][r]=v.z; Tl[seg+i*4+3][r]=v.w; } }
  __syncthreads();
  int L = slen[b];
  int dr = t>>2, sc = (t&3)*16;
  union U16 { unsigned short u[8]; uint4 v; };
  U16 H[2], Lo[2];
  #pragma unroll
  for (int g=0; g<2; g++)
    #pragma unroll
    for (int i=0;i<8;i++){
      int si = sc + g*8 + i;
      float x = (s0+si < L) ? Tl[dr][si] : 0.f;
      _Float16 hh = (_Float16)x;
      float lo = x - (float)hh;
      H[g].u[i]  = __builtin_bit_cast(unsigned short, hh);
      Lo[g].u[i] = __builtin_bit_cast(unsigned short, (_Float16)lo);
    }
  size_t o = ((size_t)b*D_ + d0+dr)*S_ + s0 + sc;
  *(uint4*)(Xvh+o)   = H[0].v;  *(uint4*)(Xvh+o+8) = H[1].v;
  *(uint4*)(Xvl+o)   = Lo[0].v; *(uint4*)(Xvl+o+8) = Lo[1].v;
}

// ---------------- MFMA Gram -> A matrices (upper 128-tiles incl. diagonal) ----------------
__global__ __launch_bounds__(TPB,2) void k_gram(const unsigned short* __restrict__ Xvh,
                                                const unsigned short* __restrict__ Xvl,
                                                const unsigned int* __restrict__ wpbits,
                                                const float* __restrict__ mu,
                                                const float* __restrict__ cnt,
                                                const int* __restrict__ slen,
                                                float* __restrict__ A)
{
  __shared__ unsigned short sAvh[128][32], sAvl[128][32], sAph[128][32], sApl[128][32],
                            sBvh[128][32], sBvl[128][32];
  int id = blockIdx.x;
  int g = id>>3;
  int b = (g/10)*8 + (id&7);
  int z = g%10;
  int ti=0; while (z >= 4-ti){ z -= 4-ti; ti++; } int tj = ti + z;
  int i0 = ti*128, j0 = tj*128;
  int t = threadIdx.x, lane = t&63, w = t>>6;
  int wr = w>>1, wc = w&1, l15 = lane&15;

  f32x4 acc_t[4][4], acc_p[4][4];
  f32x4 z4 = {0.f,0.f,0.f,0.f};
  #pragma unroll
  for (int mf=0;mf<4;mf++)
    #pragma unroll
    for (int nf=0;nf<4;nf++){ acc_t[mf][nf]=z4; acc_p[mf][nf]=z4; }

  const size_t baseA = ((size_t)b*D_ + i0)*S_;
  const size_t baseB = ((size_t)b*D_ + j0)*S_;
  int phx = (lane>>4) ^ ((l15>>1)&3);

  for (int ks=0; ks<16; ks++){
    int s0 = ks*32;
    unsigned int wpw = wpbits[b*16 + ks];
    __syncthreads();
    #pragma unroll
    for (int h=0; h<2; h++){
      int ci = t + h*256;
      int row = ci>>2, cpos = ci&3;
      int ph = cpos ^ ((row>>1)&3);
      size_t ga = baseA + (size_t)row*S_ + s0 + cpos*8;
      size_t gb = baseB + (size_t)row*S_ + s0 + cpos*8;
      uint4 vh = *(const uint4*)(Xvh+ga);
      uint4 vl = *(const uint4*)(Xvl+ga);
      uint4 bh = *(const uint4*)(Xvh+gb);
      uint4 bl = *(const uint4*)(Xvl+gb);
      unsigned int m8 = (wpw >> (cpos*8)) & 0xFFu;
      uint4 mk;
      mk.x = ((m8&1u)?0xFFFFu:0u)  | ((m8&2u)?0xFFFF0000u:0u);
      mk.y = ((m8&4u)?0xFFFFu:0u)  | ((m8&8u)?0xFFFF0000u:0u);
      mk.z = ((m8&16u)?0xFFFFu:0u) | ((m8&32u)?0xFFFF0000u:0u);
      mk.w = ((m8&64u)?0xFFFFu:0u) | ((m8&128u)?0xFFFF0000u:0u);
      uint4 p4, q4;
      p4.x = vh.x&mk.x; p4.y = vh.y&mk.y; p4.z = vh.z&mk.z; p4.w = vh.w&mk.w;
      q4.x = vl.x&mk.x; q4.y = vl.y&mk.y; q4.z = vl.z&mk.z; q4.w = vl.w&mk.w;
      *(uint4*)&sAvh[row][ph*8] = vh;
      *(uint4*)&sAvl[row][ph*8] = vl;
      *(uint4*)&sAph[row][ph*8] = p4;
      *(uint4*)&sApl[row][ph*8] = q4;
      *(uint4*)&sBvh[row][ph*8] = bh;
      *(uint4*)&sBvl[row][ph*8] = bl;
    }
    __syncthreads();
    f16x8 Avh[4], Avl[4], Aph[4], Apl[4];
    #pragma unroll
    for (int mf=0;mf<4;mf++){
      int r = wr*64 + mf*16 + l15;
      Avh[mf] = __builtin_bit_cast(f16x8, *(const uint4*)&sAvh[r][phx*8]);
      Avl[mf] = __builtin_bit_cast(f16x8, *(const uint4*)&sAvl[r][phx*8]);
      Aph[mf] = __builtin_bit_cast(f16x8, *(const uint4*)&sAph[r][phx*8]);
      Apl[mf] = __builtin_bit_cast(f16x8, *(const uint4*)&sApl[r][phx*8]);
    }
    #pragma unroll
    for (int nf=0;nf<4;nf++){
      int r = wc*64 + nf*16 + l15;
      f16x8 Bh = __builtin_bit_cast(f16x8, *(const uint4*)&sBvh[r][phx*8]);
      f16x8 Bl = __builtin_bit_cast(f16x8, *(const uint4*)&sBvl[r][phx*8]);
      #pragma unroll
      for (int mf=0;mf<4;mf++){
        acc_t[mf][nf] = __builtin_amdgcn_mfma_f32_16x16x32_f16(Avh[mf], Bh, acc_t[mf][nf],0,0,0);
        acc_t[mf][nf] = __builtin_amdgcn_mfma_f32_16x16x32_f16(Avh[mf], Bl, acc_t[mf][nf],0,0,0);
        acc_t[mf][nf] = __builtin_amdgcn_mfma_f32_16x16x32_f16(Avl[mf], Bh, acc_t[mf][nf],0,0,0);
        acc_p[mf][nf] = __builtin_amdgcn_mfma_f32_16x16x32_f16(Aph[mf], Bh, acc_p[mf][nf],0,0,0);
        acc_p[mf][nf] = __builtin_amdgcn_mfma_f32_16x16x32_f16(Aph[mf], Bl, acc_p[mf][nf],0,0,0);
        acc_p[mf][nf] = __builtin_amdgcn_mfma_f32_16x16x32_f16(Apl[mf], Bh, acc_p[mf][nf],0,0,0);
      }
    }
  }
  float cn = cnt[b*2+0], cp = cnt[b*2+1];
  float stv = (float)slen[b];
  float kn = 0.1f/(cn-1.f), kp = 0.1f/(cp-1.f), kt = 0.9f/(stv-1.f);
  float rn = 0.1f*cn/(cn-1.f), rp = 0.1f*cp/(cp-1.f), rt = 0.9f*stv/(stv-1.f);
  const float* mb = mu + (size_t)b*3*D_;
  float* A0 = A + (size_t)(b*2+0)*D_*D_;
  float* A1 = A + (size_t)(b*2+1)*D_*D_;
  int rbase = i0 + wr*64 + (lane>>4)*4;
  int cbase = j0 + wc*64 + l15;
  #pragma unroll
  for (int mf=0;mf<4;mf++){
    #pragma unroll
    for (int i=0;i<4;i++){
      int r = rbase + mf*16 + i;
      float mnr = mb[r], mpr = mb[D_+r], mtr = mb[2*D_+r];
      #pragma unroll
      for (int nf=0;nf<4;nf++){
        int c = cbase + nf*16;
        float mnc = mb[c], mpc = mb[D_+c], mtc = mb[2*D_+c];
        float gp = acc_p[mf][nf][i];
        float gt = acc_t[mf][nf][i];
        float gn = gt - gp;
        float diag = (r==c)?0.1f:0.f;
        A0[(size_t)r*D_ + c] = kn*gn + kt*gt - rn*mnr*mnc - rt*mtr*mtc + diag;
        A1[(size_t)r*D_ + c] = kp*gp + kt*gt - rp*mpr*mpc - rt*mtr*mtc + diag;
      }
    }
  }
}

// ---------------- diag finish: factor C (in LDS Ld pitch 68), 4-lane inverse, write invDT ----------------
__device__ __forceinline__ void diag_finish(float* Ld, float* __restrict__ Ig, int t)
{
  for (int k=0;k<64;k++){
    if (t==0) Ld[k*68+k] = sqrtf(Ld[k*68+k]);
    __syncthreads();
    if (t>k && t<64) Ld[t*68+k] /= Ld[k*68+k];
    __syncthreads();
    for (int l=t; l<4096; l+=TPB){
      int r=l>>6, c=l&63;
      if (r>k && c>k) Ld[r*68+c] = fmaf(-Ld[r*68+k], Ld[c*68+k], Ld[r*68+c]);
    }
    __syncthreads();
  }
  // 4-lane-per-column register-resident triangular inverse (R5/R6-proven)
  int c = t>>2, s = t&3;
  float myv[16];
  #pragma unroll
  for (int i=0;i<16;i++) myv[i] = 0.f;
  if (s==0) myv[0] = 1.f/Ld[c*68+c];
  for (int r=c+1;r<64;r++){
    float partial = 0.f;
    #pragma unroll
    for (int idx=0; idx<16; idx++){
      int k2 = c + s + 4*idx;
      if (k2 < r) partial = fmaf(Ld[r*68+k2], myv[idx], partial);
    }
    partial += __shfl_xor(partial, 1, 64);
    partial += __shfl_xor(partial, 2, 64);
    float val = -partial / Ld[r*68+r];
    int d = r - c;
    #pragma unroll
    for (int idx=0; idx<16; idx++)
      if ((d & 3) == s && (d >> 2) == idx) myv[idx] = val;
  }
  #pragma unroll
  for (int idx=0; idx<16; idx++){
    int k2 = c + s + 4*idx;
    if (k2 < 64) Ig[c*64 + k2] = myv[idx];     // invDT[c][k2] = Iv[k2][c]
  }
}

// ---------------- diag(0): factor upper(0,0) -> invDT(0) ----------------
__global__ __launch_bounds__(TPB) void k_diag0(float* __restrict__ A, float* __restrict__ invDT)
{
  int m, du; decode_mt(blockIdx.x, 1, m, du); (void)du;
  int t = threadIdx.x;
  __shared__ float Ld[64*68];
  const float* Cd = A + (size_t)m*D_*D_;
  { int r = t>>2, seg = (t&3)*16;
    #pragma unroll
    for (int i=0;i<4;i++) *((float4*)&Ld[r*68 + seg + i*4]) = *((const float4*)(Cd + (size_t)r*D_ + seg + i*4)); }
  __syncthreads();
  diag_finish(Ld, invDT + (size_t)m*8*4096, t);
}

// ---------------- panel: upper(j,ib) <- invD * upper(j,ib); emit f16T hi/lo ----------------
__global__ __launch_bounds__(TPB) void k_panel(float* __restrict__ A,
                                               const float* __restrict__ invDT,
                                               unsigned short* __restrict__ Ut,
                                               int j, int W)
{
  int m, ti; decode_mt(blockIdx.x, W, m, ti);
  int ib = j + 1 + ti;
  int t = threadIdx.x, tr = t&15, tc = t>>4;
  __shared__ float Ta[64][68], Tb[64][68];
  float* U = A + (size_t)m*D_*D_ + (size_t)(j*NB)*D_ + ib*NB;
  stage_D(invDT + ((size_t)m*8 + j)*4096, 64, Ta, t);
  stage_D(U, D_, Tb, t);
  __syncthreads();
  float acc[4][4] = {};
  mm_acc68(Ta, Tb, acc, tr, tc);
  #pragma unroll
  for (int u=0;u<4;u++){
    float4 o = make_float4(acc[u][0],acc[u][1],acc[u][2],acc[u][3]);
    *((float4*)(U + (size_t)(tr*4+u)*D_ + tc*4)) = o;
  }
  __syncthreads();
  unsigned short* shh = (unsigned short*)Ta;
  unsigned short* shl = (unsigned short*)Tb;
  #pragma unroll
  for (int u=0;u<4;u++)
    #pragma unroll
    for (int v=0;v<4;v++){
      float val = acc[u][v];                  // P[x=tr*4+u][y=tc*4+v]
      _Float16 h = (_Float16)val;
      float lo = val - (float)h;
      shh[(tc*4+v)*72 + tr*4+u] = __builtin_bit_cast(unsigned short, h);
      shl[(tc*4+v)*72 + tr*4+u] = __builtin_bit_cast(unsigned short, (_Float16)lo);
    }
  __syncthreads();
  unsigned short* Ub = Ut + ((size_t)m*28 + pidx(j, ib)) * 8192;
  { int r = t>>2, cs = (t&3)*16;
    *(uint4*)(Ub + r*64 + cs)          = *(uint4*)&shh[r*72 + cs];
    *(uint4*)(Ub + r*64 + cs + 8)      = *(uint4*)&shh[r*72 + cs + 8];
    *(uint4*)(Ub + 4096 + r*64 + cs)   = *(uint4*)&shl[r*72 + cs];
    *(uint4*)(Ub + 4096 + r*64 + cs+8) = *(uint4*)&shl[r*72 + cs + 8];
  }
}

// ---------------- MFMA trail helpers ----------------
__device__ __forceinline__ void trail_stage(const unsigned short* __restrict__ Ua,
                                            const unsigned short* __restrict__ Ub,
                                            unsigned short (*Ah)[72], unsigned short (*Al)[72],
                                            unsigned short (*Bh)[72], unsigned short (*Bl)[72],
                                            int t)
{
  int r = t>>2, cs = (t&3)*16;
  *(uint4*)&Ah[r][cs]   = *(const uint4*)(Ua + r*64 + cs);
  *(uint4*)&Ah[r][cs+8] = *(const uint4*)(Ua + r*64 + cs + 8);
  *(uint4*)&Al[r][cs]   = *(const uint4*)(Ua + 4096 + r*64 + cs);
  *(uint4*)&Al[r][cs+8] = *(const uint4*)(Ua + 4096 + r*64 + cs + 8);
  *(uint4*)&Bh[r][cs]   = *(const uint4*)(Ub + r*64 + cs);
  *(uint4*)&Bh[r][cs+8] = *(const uint4*)(Ub + r*64 + cs + 8);
  *(uint4*)&Bl[r][cs]   = *(const uint4*)(Ub + 4096 + r*64 + cs);
  *(uint4*)&Bl[r][cs+8] = *(const uint4*)(Ub + 4096 + r*64 + cs + 8);
}

__device__ __forceinline__ void trail_mfma(const unsigned short (*Ah)[72], const unsigned short (*Al)[72],
                                           const unsigned short (*Bh)[72], const unsigned short (*Bl)[72],
                                           f32x4 acc[4], int w, int l15, int lk)
{
  #pragma unroll
  for (int s=0;s<2;s++){
    f16x8 Afh = __builtin_bit_cast(f16x8, *(const uint4*)&Ah[w*16 + l15][s*32 + lk*8]);
    f16x8 Afl = __builtin_bit_cast(f16x8, *(const uint4*)&Al[w*16 + l15][s*32 + lk*8]);
    #pragma unroll
    for (int ni=0;ni<4;ni++){
      f16x8 Bfh = __builtin_bit_cast(f16x8, *(const uint4*)&Bh[ni*16 + l15][s*32 + lk*8]);
      f16x8 Bfl = __builtin_bit_cast(f16x8, *(const uint4*)&Bl[ni*16 + l15][s*32 + lk*8]);
      acc[ni] = __builtin_amdgcn_mfma_f32_16x16x32_f16(Afh, Bfh, acc[ni],0,0,0);
      acc[ni] = __builtin_amdgcn_mfma_f32_16x16x32_f16(Afh, Bfl, acc[ni],0,0,0);
      acc[ni] = __builtin_amdgcn_mfma_f32_16x16x32_f16(Afl, Bfh, acc[ni],0,0,0);
    }
  }
}

__device__ __forceinline__ void trail_rmw(float* __restrict__ Cb, const f32x4 acc[4],
                                          int w, int l15, int lk)
{
  #pragma unroll
  for (int ni=0;ni<4;ni++)
    #pragma unroll
    for (int i=0;i<4;i++){
      int r = w*16 + lk*4 + i, cc = ni*16 + l15;
      float* pC = Cb + (size_t)r*D_ + cc;
      *pC -= acc[ni][i];
    }
}

// fused: C(dblk,dblk) -= acc (in LDS), factor, invDT(dblk)
__device__ __forceinline__ void fused_diag(float* __restrict__ A, float* __restrict__ invDT,
                                           float* Ld, const f32x4 acc[4],
                                           int m, int dblk, int t, int w, int l15, int lk)
{
  const float* Cd = A + (size_t)m*D_*D_ + (size_t)(dblk*NB)*D_ + dblk*NB;
  { int r = t>>2, seg = (t&3)*16;
    #pragma unroll
    for (int i=0;i<4;i++) *((float4*)&Ld[r*68 + seg + i*4]) = *((const float4*)(Cd + (size_t)r*D_ + seg + i*4)); }
  __syncthreads();
  #pragma unroll
  for (int ni=0;ni<4;ni++)
    #pragma unroll
    for (int i=0;i<4;i++)
      Ld[(w*16 + lk*4 + i)*68 + ni*16 + l15] -= acc[ni][i];
  __syncthreads();
  diag_finish(Ld, invDT + ((size_t)m*8 + dblk)*4096, t);
}

// ---------------- trailrow (MFMA): upper(row,b) -= U(j,row)^T U(j,b); z=0 fuses diag(row) ----------------
__global__ __launch_bounds__(TPB) void k_trailrow(float* __restrict__ A,
                                                  const unsigned short* __restrict__ Ut,
                                                  float* __restrict__ invDT,
                                                  int j, int row, int W)
{
  int m, z; decode_mt(blockIdx.x, W, m, z);
  int b2 = row + z;
  int t = threadIdx.x, lane = t&63, w = t>>6, l15 = lane&15, lk = lane>>4;
  __shared__ unsigned short sbuf[4*64*72];
  unsigned short (*Ah)[72] = (unsigned short(*)[72])sbuf;
  unsigned short (*Al)[72] = (unsigned short(*)[72])(sbuf + 64*72);
  unsigned short (*Bh)[72] = (unsigned short(*)[72])(sbuf + 2*64*72);
  unsigned short (*Bl)[72] = (unsigned short(*)[72])(sbuf + 3*64*72);
  const unsigned short* Um = Ut + (size_t)m*28*8192;
  trail_stage(Um + (size_t)pidx(j,row)*8192, Um + (size_t)pidx(j,b2)*8192, Ah, Al, Bh, Bl, t);
  __syncthreads();
  f32x4 acc[4];
  #pragma unroll
  for (int ni=0;ni<4;ni++) acc[ni] = (f32x4){0.f,0.f,0.f,0.f};
  trail_mfma(Ah, Al, Bh, Bl, acc, w, l15, lk);
  if (z == 0){
    __syncthreads();   // done reading sbuf; reuse as Ld
    fused_diag(A, invDT, (float*)sbuf, acc, m, row, t, w, l15, lk);
  } else {
    float* Cb = A + (size_t)m*D_*D_ + (size_t)(row*NB)*D_ + b2*NB;
    trail_rmw(Cb, acc, w, l15, lk);
  }
}

// ---------------- trail2 (MFMA): upper(a,b) -= cols jb,jb+1; z=0 fuses diag(jb+2) ----------------
__global__ __launch_bounds__(TPB) void k_trail2(float* __restrict__ A,
                                                const unsigned short* __restrict__ Ut,
                                                float* __restrict__ invDT,
                                                int jb, int W)
{
  int m, z; decode_mt(blockIdx.x, W, m, z);
  int base = jb + 2;
  int Tn = NT - base;
  int p = 0, zz = z;
  while (zz >= Tn - p){ zz -= Tn - p; p++; }
  int a2 = base + p, b2 = a2 + zz;
  int t = threadIdx.x, lane = t&63, w = t>>6, l15 = lane&15, lk = lane>>4;
  __shared__ unsigned short sbuf[4*64*72];
  unsigned short (*Ah)[72] = (unsigned short(*)[72])sbuf;
  unsigned short (*Al)[72] = (unsigned short(*)[72])(sbuf + 64*72);
  unsigned short (*Bh)[72] = (unsigned short(*)[72])(sbuf + 2*64*72);
  unsigned short (*Bl)[72] = (unsigned short(*)[72])(sbuf + 3*64*72);
  const unsigned short* Um = Ut + (size_t)m*28*8192;
  f32x4 acc[4];
  #pragma unroll
  for (int ni=0;ni<4;ni++) acc[ni] = (f32x4){0.f,0.f,0.f,0.f};
  #pragma unroll
  for (int c=0;c<2;c++){
    int j = jb + c;
    __syncthreads();
    trail_stage(Um + (size_t)pidx(j,a2)*8192, Um + (size_t)pidx(j,b2)*8192, Ah, Al, Bh, Bl, t);
    __syncthreads();
    trail_mfma(Ah, Al, Bh, Bl, acc, w, l15, lk);
  }
  if (z == 0){
    __syncthreads();
    fused_diag(A, invDT, (float*)sbuf, acc, m, base, t, w, l15, lk);
  } else {
    float* Cb = A + (size_t)m*D_*D_ + (size_t)(a2*NB)*D_ + b2*NB;
    trail_rmw(Cb, acc, w, l15, lk);
  }
}

// ---------------- fused rform + forward solve + maha + logits (128 q / block) ----------------
__global__ __launch_bounds__(TPB) void k_solvefin(const float* __restrict__ Qs,
                                                  const float* __restrict__ mu,
                                                  const float* __restrict__ A,
                                                  const float* __restrict__ invDT,
                                                  float* __restrict__ Z,
                                                  const int* __restrict__ qlen,
                                                  const float* __restrict__ lps,
                                                  float* __restrict__ out)
{
  int m, t0; decode_mt(blockIdx.x, 2, m, t0);
  int q0 = t0*128;
  int b = m>>1, cls = m&1;
  int t = threadIdx.x, tr = t&15, tc = t>>4;
  __shared__ float Ta[64][68];
  __shared__ float Tb[64][136];
  const float* Am = A + (size_t)m*D_*D_;
  float* Zm = Z + (size_t)m*D_*Q_;
  const float* muv = mu + ((size_t)b*3 + cls)*D_;
  float cs[2][4] = {};
  for (int j=0;j<NT;j++){
    float acc[2][4][4];
    {
      float4 mv = *(const float4*)&muv[j*NB + tr*4];
      #pragma unroll
      for (int h=0;h<2;h++)
        #pragma unroll
        for (int v=0;v<4;v++){
          float4 qv = *(const float4*)&Qs[((size_t)b*Q_ + q0 + h*64 + tc*4 + v)*D_ + j*NB + tr*4];
          acc[h][0][v] = mv.x - qv.x;
          acc[h][1][v] = mv.y - qv.y;
          acc[h][2][v] = mv.z - qv.z;
          acc[h][3][v] = mv.w - qv.w;
        }
    }
    for (int k=0;k<j;k++){
      stage_D(Am + (size_t)(k*NB)*D_ + j*NB, D_, Ta, t);
      { int r = t >> 2, seg = (t & 3)*16;
        #pragma unroll
        for (int h=0;h<2;h++){
          const float4* s4 = (const float4*)(Zm + (size_t)(k*NB + r)*Q_ + q0 + h*64 + seg);
          #pragma unroll
          for (int i=0;i<4;i++) *((float4*)&Tb[r][h*68 + seg + i*4]) = s4[i];
        }
      }
      __syncthreads();
      for (int kk=0;kk<64;kk++){
        float4 av = *((const float4*)&Ta[kk][tr*4]);
        float4 bv0 = *((const float4*)&Tb[kk][tc*4]);
        float4 bv1 = *((const float4*)&Tb[kk][68 + tc*4]);
        float a[4]={av.x,av.y,av.z,av.w};
        float b0[4]={bv0.x,bv0.y,bv0.z,bv0.w}, b1[4]={bv1.x,bv1.y,bv1.z,bv1.w};
        #pragma unroll
        for (int u=0;u<4;u++)
          #pragma unroll
          for (int v=0;v<4;v++){
            acc[0][u][v] = fmaf(-a[u], b0[v], acc[0][u][v]);
            acc[1][u][v] = fmaf(-a[u], b1[v], acc[1][u][v]);
          }
      }
      __syncthreads();
    }
    // Z_j = invD * S  (both 64-q halves)
    #pragma unroll
    for (int h=0;h<2;h++)
      #pragma unroll
      for (int u=0;u<4;u++)
        #pragma unroll
        for (int v=0;v<4;v++) Tb[tr*4+u][h*68 + tc*4+v] = acc[h][u][v];
    stage_D(invDT + ((size_t)m*8 + j)*4096, 64, Ta, t);
    __syncthreads();
    float o4[2][4][4] = {};
    for (int kk=0;kk<64;kk++){
      float4 av = *((const float4*)&Ta[kk][tr*4]);
      float4 bv0 = *((const float4*)&Tb[kk][tc*4]);
      float4 bv1 = *((const float4*)&Tb[kk][68 + tc*4]);
      float a[4]={av.x,av.y,av.z,av.w};
      float b0[4]={bv0.x,bv0.y,bv0.z,bv0.w}, b1[4]={bv1.x,bv1.y,bv1.z,bv1.w};
      #pragma unroll
      for (int u=0;u<4;u++)
        #pragma unroll
        for (int v=0;v<4;v++){
          o4[0][u][v] = fmaf(a[u], b0[v], o4[0][u][v]);
          o4[1][u][v] = fmaf(a[u], b1[v], o4[1][u][v]);
        }
    }
    if (j < NT-1){
      #pragma unroll
      for (int h=0;h<2;h++)
        #pragma unroll
        for (int u=0;u<4;u++){
          float4 o = make_float4(o4[h][u][0], o4[h][u][1], o4[h][u][2], o4[h][u][3]);
          *((float4*)(Zm + (size_t)(j*NB + tr*4+u)*Q_ + q0 + h*64 + tc*4)) = o;
        }
    }
    #pragma unroll
    for (int h=0;h<2;h++)
      #pragma unroll
      for (int u=0;u<4;u++)
        #pragma unroll
        for (int v=0;v<4;v++) cs[h][v] = fmaf(o4[h][u][v], o4[h][u][v], cs[h][v]);
    __syncthreads();
  }
  float* red = &Tb[0][0];
  #pragma unroll
  for (int h=0;h<2;h++)
    #pragma unroll
    for (int v=0;v<4;v++) red[(h*64 + tc*4+v)*16 + tr] = cs[h][v];
  __syncthreads();
  if (t < 128){
    float s = 0.f;
    #pragma unroll
    for (int i=0;i<16;i++) s += red[t*16 + i];
    int q = q0 + t;
    float valid = (q < qlen[b]) ? 1.f : 0.f;
    float s2 = expf(2.f*lps[0]);
    out[((size_t)b*Q_ + q)*2 + cls] = -s2*s*valid;
  }
}

extern "C" void kernel_launch(void* const* d_in, const int* in_sizes, int n_in,
                              void* d_out, int out_size, void* d_ws, size_t ws_size,
                              hipStream_t stream) {
  (void)in_sizes; (void)n_in; (void)out_size;
  const float* X   = (const float*)d_in[0];
  const int*   lab = (const int*)d_in[1];
  const float* Qs  = (const float*)d_in[2];
  const int*   sl  = (const int*)d_in[3];
  const int*   ql  = (const int*)d_in[4];
  const float* lps = (const float*)d_in[5];
  float* out = (float*)d_out;

  float* A  = (float*)d_ws;                          // [512,512,512] f32
  float* Z  = A + (size_t)NM_*D_*D_;                 // [512,512,256] f32
  unsigned short* Xvh = (unsigned short*)Z;          // overlays Z (gram phase only)
  unsigned short* Xvl = Xvh + (size_t)B_*D_*S_;
  unsigned short* Ut  = (unsigned short*)Z;          // overlays Z (chol phase only): [512][28][8192]
  float* invDT = Z + (size_t)NM_*D_*Q_;              // [512,8,64,64] f32 (transposed)
  float* mu   = invDT + (size_t)NM_*8*64*64;         // [256,3,512]
  float* cnt  = mu + (size_t)B_*3*D_;                // [256,2]
  unsigned int* wpbits = (unsigned int*)(cnt + B_*2);// [256,16]
  size_t need = (size_t)((char*)(wpbits + B_*16) - (char*)d_ws);
  if (ws_size < need) return;

  k_stats<<<dim3(B_), dim3(1024), 0, stream>>>(X, lab, sl, mu, cnt, wpbits);
  k_prep<<<dim3(64, B_), dim3(TPB), 0, stream>>>(X, sl, Xvh, Xvl);
  k_gram<<<dim3(2560), dim3(TPB), 0, stream>>>(Xvh, Xvl, wpbits, mu, cnt, sl, A);

  // lazy two-column Cholesky, diag fused into trail z=0 (15 launches total)
  k_diag0<<<dim3(NM_), dim3(TPB), 0, stream>>>(A, invDT);
  for (int j=0; j<NT; j+=2){
    int nb0 = NT-1-j;
    k_panel<<<dim3(NM_*nb0), dim3(TPB), 0, stream>>>(A, invDT, Ut, j, nb0);
    int wr = NT-1-j;                 // row j+1 tiles: b = j+1 .. 7 ; z=0 fuses diag(j+1)
    k_trailrow<<<dim3(NM_*wr), dim3(TPB), 0, stream>>>(A, Ut, invDT, j, j+1, wr);
    int nb1 = NT-1-(j+1);
    if (nb1 > 0){
      k_panel<<<dim3(NM_*nb1), dim3(TPB), 0, stream>>>(A, invDT, Ut, j+1, nb1);
      int Tn = NT - (j+2);
      int np = Tn*(Tn+1)/2;          // z=0 fuses diag(j+2)
      if (np > 0) k_trail2<<<dim3(NM_*np), dim3(TPB), 0, stream>>>(A, Ut, invDT, j, np);
    }
  }

  k_solvefin<<<dim3(NM_*2), dim3(TPB), 0, stream>>>(Qs, mu, A, invDT, Z, ql, lps, out);
}

// Round 11
// 2568.692 us; speedup vs baseline: 1.0437x; 1.0437x over previous
//
#include <hip/hip_runtime.h>
#include <hip/hip_bf16.h>

#define TPB 256
constexpr int B_ = 256, S_ = 512, D_ = 512, Q_ = 256, NM_ = 512;
constexpr int NB = 64, NT = 8;

typedef _Float16 f16x8 __attribute__((ext_vector_type(8)));
typedef float f32x4 __attribute__((ext_vector_type(4)));

__device__ __forceinline__ int pidx(int j, int a){ return j*(15-j)/2 + (a-j-1); } // j<a, 28 tiles

// XCD-co-locating decode: x=bid&7 -> XCD; per XCD: tasks fastest, then cls, then group.
__device__ __forceinline__ void decode_mt(int bid, int W, int& m, int& t){
  int x = bid & 7, r = bid >> 3;
  t = r % W; int u = r / W;
  m = (((u >> 1)*8 + x) << 1) | (u & 1);
}

// direct row-major 64x64 stage into pitch-68 LDS (256 threads)
__device__ __forceinline__ void stage_D(const float* __restrict__ src, size_t ld,
                                        float (*dst)[68], int t)
{
  int r = t >> 2, seg = (t & 3) * 16;
  const float4* s4 = (const float4*)(src + (size_t)r*ld + seg);
  #pragma unroll
  for (int i=0;i<4;i++) *((float4*)&dst[r][seg + i*4]) = s4[i];
}

// acc[u][v] += sum_kk Aop[kk][tr*4+u] * Bop[kk][tc*4+v]
__device__ __forceinline__ void mm_acc68(const float (*Aop)[68], const float (*Bop)[68],
                                         float acc[4][4], int tr, int tc)
{
  for (int kk=0;kk<64;kk++){
    float4 av = *((const float4*)&Aop[kk][tr*4]);
    float4 bv = *((const float4*)&Bop[kk][tc*4]);
    float a[4]={av.x,av.y,av.z,av.w}, b2[4]={bv.x,bv.y,bv.z,bv.w};
    #pragma unroll
    for (int u=0;u<4;u++)
      #pragma unroll
      for (int v=0;v<4;v++) acc[u][v] = fmaf(a[u], b2[v], acc[u][v]);
  }
}

// ---------------- stats: counts, means, pos bitmask (1024 thr, 4-way s-split) ----------------
__global__ __launch_bounds__(1024) void k_stats(const float* __restrict__ X,
                                                const int* __restrict__ labels,
                                                const int* __restrict__ slen,
                                                float* __restrict__ mu,
                                                float* __restrict__ cnt,
                                                unsigned int* __restrict__ wpbits)
{
  int b = blockIdx.x, t = threadIdx.x;
  int td = t & 255, sg = t >> 8;
  __shared__ int lab[S_];
  __shared__ float red[1024];
  __shared__ float part[4][256][4];
  int L = slen[b];
  if (t < S_) {
    int lb = labels[b*S_ + t];
    lab[t] = (t < L) ? lb : -1;
  }
  __syncthreads();
  if (t < 16) {
    unsigned int wword = 0;
    for (int i2 = 0; i2 < 32; i2++) if (lab[t*32 + i2] == 1) wword |= (1u << i2);
    wpbits[b*16 + t] = wword;
  }
  red[t] = (t < S_) ? ((lab[t]==1) ? 1.f : 0.f) : 0.f;
  __syncthreads();
  for (int o=512;o>0;o>>=1){ if(t<o) red[t]+=red[t+o]; __syncthreads(); }
  float cp = red[0]; __syncthreads();
  red[t] = (t < S_) ? ((lab[t]==0) ? 1.f : 0.f) : 0.f;
  __syncthreads();
  for (int o=512;o>0;o>>=1){ if(t<o) red[t]+=red[t+o]; __syncthreads(); }
  float cn = red[0];
  if (t==0){ cnt[b*2+0]=cn; cnt[b*2+1]=cp; }
  float sp0=0,sp1=0,sn0=0,sn1=0;
  const float* Xb = X + (size_t)b*S_*D_;
  for (int s=sg*128; s<sg*128+128; s++){
    int e = lab[s];
    if (e < 0) continue;
    float x0 = Xb[(size_t)s*D_ + td];
    float x1 = Xb[(size_t)s*D_ + td + 256];
    if (e==1){ sp0+=x0; sp1+=x1; } else { sn0+=x0; sn1+=x1; }
  }
  part[sg][td][0]=sn0; part[sg][td][1]=sn1; part[sg][td][2]=sp0; part[sg][td][3]=sp1;
  __syncthreads();
  if (sg == 0){
    float a0=0,a1=0,a2=0,a3=0;
    #pragma unroll
    for (int g=0;g<4;g++){ a0+=part[g][td][0]; a1+=part[g][td][1]; a2+=part[g][td][2]; a3+=part[g][td][3]; }
    float stv = (float)L;
    float* mb = mu + (size_t)b*3*D_;
    mb[0*D_ + td] = a0/cn;      mb[0*D_ + td+256] = a1/cn;
    mb[1*D_ + td] = a2/cp;      mb[1*D_ + td+256] = a3/cp;
    mb[2*D_ + td] = (a0+a2)/stv; mb[2*D_ + td+256] = (a1+a3)/stv;
  }
}

// ---------------- prep: transpose X -> f16 hi/lo [B][D][S], valid-masked ----------------
__global__ __launch_bounds__(TPB) void k_prep(const float* __restrict__ X,
                                              const int* __restrict__ slen,
                                              unsigned short* __restrict__ Xvh,
                                              unsigned short* __restrict__ Xvl)
{
  int b = blockIdx.y, z = blockIdx.x;
  int d0 = (z>>3)*64, s0 = (z&7)*64;
  int t = threadIdx.x;
  __shared__ float Tl[64][65];
  const float* src = X + ((size_t)b*S_ + s0)*D_ + d0;
  { int r = t>>2, seg = (t&3)*16;
    const float4* s4 = (const float4*)(src + (size_t)r*D_ + seg);
    #pragma unroll
    for (int i=0;i<4;i++){ float4 v = s4[i];
      Tl[seg+i*4+0][r]=v.x; Tl[seg+i*4+1][r]=v.y; Tl[seg+i*4+2][r]=v.z; Tl[seg+i*4+3][r]=v.w; } }
  __syncthreads();
  int L = slen[b];
  int dr = t>>2, sc = (t&3)*16;
  union U16 { unsigned short u[8]; uint4 v; };
  U16 H[2], Lo[2];
  #pragma unroll
  for (int g=0; g<2; g++)
    #pragma unroll
    for (int i=0;i<8;i++){
      int si = sc + g*8 + i;
      float x = (s0+si < L) ? Tl[dr][si] : 0.f;
      _Float16 hh = (_Float16)x;
      float lo = x - (float)hh;
      H[g].u[i]  = __builtin_bit_cast(unsigned short, hh);
      Lo[g].u[i] = __builtin_bit_cast(unsigned short, (_Float16)lo);
    }
  size_t o = ((size_t)b*D_ + d0+dr)*S_ + s0 + sc;
  *(uint4*)(Xvh+o)   = H[0].v;  *(uint4*)(Xvh+o+8) = H[1].v;
  *(uint4*)(Xvl+o)   = Lo[0].v; *(uint4*)(Xvl+o+8) = Lo[1].v;
}

// ---------------- MFMA Gram -> A matrices (upper 128-tiles incl. diagonal) ----------------
__global__ __launch_bounds__(TPB,2) void k_gram(const unsigned short* __restrict__ Xvh,
                                                const unsigned short* __restrict__ Xvl,
                                                const unsigned int* __restrict__ wpbits,
                                                const float* __restrict__ mu,
                                                const float* __restrict__ cnt,
                                                const int* __restrict__ slen,
                                                float* __restrict__ A)
{
  __shared__ unsigned short sAvh[128][32], sAvl[128][32], sAph[128][32], sApl[128][32],
                            sBvh[128][32], sBvl[128][32];
  int id = blockIdx.x;
  int g = id>>3;
  int b = (g/10)*8 + (id&7);
  int z = g%10;
  int ti=0; while (z >= 4-ti){ z -= 4-ti; ti++; } int tj = ti + z;
  int i0 = ti*128, j0 = tj*128;
  int t = threadIdx.x, lane = t&63, w = t>>6;
  int wr = w>>1, wc = w&1, l15 = lane&15;

  f32x4 acc_t[4][4], acc_p[4][4];
  f32x4 z4 = {0.f,0.f,0.f,0.f};
  #pragma unroll
  for (int mf=0;mf<4;mf++)
    #pragma unroll
    for (int nf=0;nf<4;nf++){ acc_t[mf][nf]=z4; acc_p[mf][nf]=z4; }

  const size_t baseA = ((size_t)b*D_ + i0)*S_;
  const size_t baseB = ((size_t)b*D_ + j0)*S_;
  int phx = (lane>>4) ^ ((l15>>1)&3);

  for (int ks=0; ks<16; ks++){
    int s0 = ks*32;
    unsigned int wpw = wpbits[b*16 + ks];
    __syncthreads();
    #pragma unroll
    for (int h=0; h<2; h++){
      int ci = t + h*256;
      int row = ci>>2, cpos = ci&3;
      int ph = cpos ^ ((row>>1)&3);
      size_t ga = baseA + (size_t)row*S_ + s0 + cpos*8;
      size_t gb = baseB + (size_t)row*S_ + s0 + cpos*8;
      uint4 vh = *(const uint4*)(Xvh+ga);
      uint4 vl = *(const uint4*)(Xvl+ga);
      uint4 bh = *(const uint4*)(Xvh+gb);
      uint4 bl = *(const uint4*)(Xvl+gb);
      unsigned int m8 = (wpw >> (cpos*8)) & 0xFFu;
      uint4 mk;
      mk.x = ((m8&1u)?0xFFFFu:0u)  | ((m8&2u)?0xFFFF0000u:0u);
      mk.y = ((m8&4u)?0xFFFFu:0u)  | ((m8&8u)?0xFFFF0000u:0u);
      mk.z = ((m8&16u)?0xFFFFu:0u) | ((m8&32u)?0xFFFF0000u:0u);
      mk.w = ((m8&64u)?0xFFFFu:0u) | ((m8&128u)?0xFFFF0000u:0u);
      uint4 p4, q4;
      p4.x = vh.x&mk.x; p4.y = vh.y&mk.y; p4.z = vh.z&mk.z; p4.w = vh.w&mk.w;
      q4.x = vl.x&mk.x; q4.y = vl.y&mk.y; q4.z = vl.z&mk.z; q4.w = vl.w&mk.w;
      *(uint4*)&sAvh[row][ph*8] = vh;
      *(uint4*)&sAvl[row][ph*8] = vl;
      *(uint4*)&sAph[row][ph*8] = p4;
      *(uint4*)&sApl[row][ph*8] = q4;
      *(uint4*)&sBvh[row][ph*8] = bh;
      *(uint4*)&sBvl[row][ph*8] = bl;
    }
    __syncthreads();
    f16x8 Avh[4], Avl[4], Aph[4], Apl[4];
    #pragma unroll
    for (int mf=0;mf<4;mf++){
      int r = wr*64 + mf*16 + l15;
      Avh[mf] = __builtin_bit_cast(f16x8, *(const uint4*)&sAvh[r][phx*8]);
      Avl[mf] = __builtin_bit_cast(f16x8, *(const uint4*)&sAvl[r][phx*8]);
      Aph[mf] = __builtin_bit_cast(f16x8, *(const uint4*)&sAph[r][phx*8]);
      Apl[mf] = __builtin_bit_cast(f16x8, *(const uint4*)&sApl[r][phx*8]);
    }
    #pragma unroll
    for (int nf=0;nf<4;nf++){
      int r = wc*64 + nf*16 + l15;
      f16x8 Bh = __builtin_bit_cast(f16x8, *(const uint4*)&sBvh[r][phx*8]);
      f16x8 Bl = __builtin_bit_cast(f16x8, *(const uint4*)&sBvl[r][phx*8]);
      #pragma unroll
      for (int mf=0;mf<4;mf++){
        acc_t[mf][nf] = __builtin_amdgcn_mfma_f32_16x16x32_f16(Avh[mf], Bh, acc_t[mf][nf],0,0,0);
        acc_t[mf][nf] = __builtin_amdgcn_mfma_f32_16x16x32_f16(Avh[mf], Bl, acc_t[mf][nf],0,0,0);
        acc_t[mf][nf] = __builtin_amdgcn_mfma_f32_16x16x32_f16(Avl[mf], Bh, acc_t[mf][nf],0,0,0);
        acc_p[mf][nf] = __builtin_amdgcn_mfma_f32_16x16x32_f16(Aph[mf], Bh, acc_p[mf][nf],0,0,0);
        acc_p[mf][nf] = __builtin_amdgcn_mfma_f32_16x16x32_f16(Aph[mf], Bl, acc_p[mf][nf],0,0,0);
        acc_p[mf][nf] = __builtin_amdgcn_mfma_f32_16x16x32_f16(Apl[mf], Bh, acc_p[mf][nf],0,0,0);
      }
    }
  }
  float cn = cnt[b*2+0], cp = cnt[b*2+1];
  float stv = (float)slen[b];
  float kn = 0.1f/(cn-1.f), kp = 0.1f/(cp-1.f), kt = 0.9f/(stv-1.f);
  float rn = 0.1f*cn/(cn-1.f), rp = 0.1f*cp/(cp-1.f), rt = 0.9f*stv/(stv-1.f);
  const float* mb = mu + (size_t)b*3*D_;
  float* A0 = A + (size_t)(b*2+0)*D_*D_;
  float* A1 = A + (size_t)(b*2+1)*D_*D_;
  int rbase = i0 + wr*64 + (lane>>4)*4;
  int cbase = j0 + wc*64 + l15;
  #pragma unroll
  for (int mf=0;mf<4;mf++){
    #pragma unroll
    for (int i=0;i<4;i++){
      int r = rbase + mf*16 + i;
      float mnr = mb[r], mpr = mb[D_+r], mtr = mb[2*D_+r];
      #pragma unroll
      for (int nf=0;nf<4;nf++){
        int c = cbase + nf*16;
        float mnc = mb[c], mpc = mb[D_+c], mtc = mb[2*D_+c];
        float gp = acc_p[mf][nf][i];
        float gt = acc_t[mf][nf][i];
        float gn = gt - gp;
        float diag = (r==c)?0.1f:0.f;
        A0[(size_t)r*D_ + c] = kn*gn + kt*gt - rn*mnr*mnc - rt*mtr*mtc + diag;
        A1[(size_t)r*D_ + c] = kp*gp + kt*gt - rp*mpr*mpc - rt*mtr*mtc + diag;
      }
    }
  }
}

// ---------------- diag block Cholesky + 4-lane register triangular inverse ----------------
__global__ __launch_bounds__(TPB) void k_diag(float* __restrict__ A,
                                              float* __restrict__ invDT, int j)
{
  int m, t0; decode_mt(blockIdx.x, 1, m, t0); (void)t0;
  int t = threadIdx.x;
  __shared__ float Ld[64][65];
  float* Ab = A + (size_t)m*D_*D_ + (size_t)(j*NB)*D_ + j*NB;
  for (int l=t; l<4096; l+=TPB){ int r=l>>6, c=l&63; Ld[r][c] = Ab[(size_t)r*D_ + c]; }
  __syncthreads();
  for (int k=0;k<64;k++){
    if (t==0) Ld[k][k] = sqrtf(Ld[k][k]);
    __syncthreads();
    if (t>k && t<64) Ld[t][k] /= Ld[k][k];
    __syncthreads();
    for (int l=t; l<4096; l+=TPB){
      int r=l>>6, c=l&63;
      if (r>k && c>k) Ld[r][c] = fmaf(-Ld[r][k], Ld[c][k], Ld[r][c]);
    }
    __syncthreads();
  }
  // 4-lane-per-column register-resident triangular inverse (R5/R6-proven), writes invDT direct
  int c = t>>2, s = t&3;
  float myv[16];
  #pragma unroll
  for (int i=0;i<16;i++) myv[i] = 0.f;
  if (s==0) myv[0] = 1.f/Ld[c][c];
  for (int r=c+1;r<64;r++){
    float partial = 0.f;
    #pragma unroll
    for (int idx=0; idx<16; idx++){
      int k2 = c + s + 4*idx;
      if (k2 < r) partial = fmaf(Ld[r][k2], myv[idx], partial);
    }
    partial += __shfl_xor(partial, 1, 64);
    partial += __shfl_xor(partial, 2, 64);
    float val = -partial / Ld[r][r];
    int d = r - c;
    #pragma unroll
    for (int idx=0; idx<16; idx++)
      if ((d & 3) == s && (d >> 2) == idx) myv[idx] = val;
  }
  float* Ig = invDT + ((size_t)m*8 + j)*4096;
  #pragma unroll
  for (int idx=0; idx<16; idx++){
    int k2 = c + s + 4*idx;
    if (k2 < 64) Ig[c*64 + k2] = myv[idx];     // invDT[c][k2] = Iv[k2][c]
  }
}

// ---------------- panel: upper(j,ib) <- invD * upper(j,ib); emit f16T hi/lo ----------------
__global__ __launch_bounds__(TPB) void k_panel(float* __restrict__ A,
                                               const float* __restrict__ invDT,
                                               unsigned short* __restrict__ Ut,
                                               int j, int W)
{
  int m, ti; decode_mt(blockIdx.x, W, m, ti);
  int ib = j + 1 + ti;
  int t = threadIdx.x, tr = t&15, tc = t>>4;
  __shared__ float Ta[64][68], Tb[64][68];
  float* U = A + (size_t)m*D_*D_ + (size_t)(j*NB)*D_ + ib*NB;
  stage_D(invDT + ((size_t)m*8 + j)*4096, 64, Ta, t);
  stage_D(U, D_, Tb, t);
  __syncthreads();
  float acc[4][4] = {};
  mm_acc68(Ta, Tb, acc, tr, tc);
  #pragma unroll
  for (int u=0;u<4;u++){
    float4 o = make_float4(acc[u][0],acc[u][1],acc[u][2],acc[u][3]);
    *((float4*)(U + (size_t)(tr*4+u)*D_ + tc*4)) = o;
  }
  __syncthreads();
  unsigned short* shh = (unsigned short*)Ta;
  unsigned short* shl = (unsigned short*)Tb;
  #pragma unroll
  for (int u=0;u<4;u++)
    #pragma unroll
    for (int v=0;v<4;v++){
      float val = acc[u][v];                  // P[x=tr*4+u][y=tc*4+v]
      _Float16 h = (_Float16)val;
      float lo = val - (float)h;
      shh[(tc*4+v)*72 + tr*4+u] = __builtin_bit_cast(unsigned short, h);
      shl[(tc*4+v)*72 + tr*4+u] = __builtin_bit_cast(unsigned short, (_Float16)lo);
    }
  __syncthreads();
  unsigned short* Ub = Ut + ((size_t)m*28 + pidx(j, ib)) * 8192;
  { int r = t>>2, cs = (t&3)*16;
    *(uint4*)(Ub + r*64 + cs)          = *(uint4*)&shh[r*72 + cs];
    *(uint4*)(Ub + r*64 + cs + 8)      = *(uint4*)&shh[r*72 + cs + 8];
    *(uint4*)(Ub + 4096 + r*64 + cs)   = *(uint4*)&shl[r*72 + cs];
    *(uint4*)(Ub + 4096 + r*64 + cs+8) = *(uint4*)&shl[r*72 + cs + 8];
  }
}

// ---------------- MFMA trail helpers ----------------
__device__ __forceinline__ void trail_stage(const unsigned short* __restrict__ Ua,
                                            const unsigned short* __restrict__ Ub,
                                            unsigned short (*Ah)[72], unsigned short (*Al)[72],
                                            unsigned short (*Bh)[72], unsigned short (*Bl)[72],
                                            int t)
{
  int r = t>>2, cs = (t&3)*16;
  *(uint4*)&Ah[r][cs]   = *(const uint4*)(Ua + r*64 + cs);
  *(uint4*)&Ah[r][cs+8] = *(const uint4*)(Ua + r*64 + cs + 8);
  *(uint4*)&Al[r][cs]   = *(const uint4*)(Ua + 4096 + r*64 + cs);
  *(uint4*)&Al[r][cs+8] = *(const uint4*)(Ua + 4096 + r*64 + cs + 8);
  *(uint4*)&Bh[r][cs]   = *(const uint4*)(Ub + r*64 + cs);
  *(uint4*)&Bh[r][cs+8] = *(const uint4*)(Ub + r*64 + cs + 8);
  *(uint4*)&Bl[r][cs]   = *(const uint4*)(Ub + 4096 + r*64 + cs);
  *(uint4*)&Bl[r][cs+8] = *(const uint4*)(Ub + 4096 + r*64 + cs + 8);
}

__device__ __forceinline__ void trail_mfma(const unsigned short (*Ah)[72], const unsigned short (*Al)[72],
                                           const unsigned short (*Bh)[72], const unsigned short (*Bl)[72],
                                           f32x4 acc[4], int w, int l15, int lk)
{
  #pragma unroll
  for (int s=0;s<2;s++){
    f16x8 Afh = __builtin_bit_cast(f16x8, *(const uint4*)&Ah[w*16 + l15][s*32 + lk*8]);
    f16x8 Afl = __builtin_bit_cast(f16x8, *(const uint4*)&Al[w*16 + l15][s*32 + lk*8]);
    #pragma unroll
    for (int ni=0;ni<4;ni++){
      f16x8 Bfh = __builtin_bit_cast(f16x8, *(const uint4*)&Bh[ni*16 + l15][s*32 + lk*8]);
      f16x8 Bfl = __builtin_bit_cast(f16x8, *(const uint4*)&Bl[ni*16 + l15][s*32 + lk*8]);
      acc[ni] = __builtin_amdgcn_mfma_f32_16x16x32_f16(Afh, Bfh, acc[ni],0,0,0);
      acc[ni] = __builtin_amdgcn_mfma_f32_16x16x32_f16(Afh, Bfl, acc[ni],0,0,0);
      acc[ni] = __builtin_amdgcn_mfma_f32_16x16x32_f16(Afl, Bfh, acc[ni],0,0,0);
    }
  }
}

__device__ __forceinline__ void trail_rmw(float* __restrict__ Cb, const f32x4 acc[4],
                                          int w, int l15, int lk)
{
  #pragma unroll
  for (int ni=0;ni<4;ni++)
    #pragma unroll
    for (int i=0;i<4;i++){
      int r = w*16 + lk*4 + i, cc = ni*16 + l15;
      float* pC = Cb + (size_t)r*D_ + cc;
      *pC -= acc[ni][i];
    }
}

// ---------------- trailrow (MFMA): upper(row,b) -= U(j,row)^T U(j,b) ----------------
__global__ __launch_bounds__(TPB) void k_trailrow(float* __restrict__ A,
                                                  const unsigned short* __restrict__ Ut,
                                                  int j, int row, int W)
{
  int m, z; decode_mt(blockIdx.x, W, m, z);
  int b2 = row + z;
  int t = threadIdx.x, lane = t&63, w = t>>6, l15 = lane&15, lk = lane>>4;
  __shared__ unsigned short Ah[64][72], Al[64][72], Bh[64][72], Bl[64][72];
  const unsigned short* Um = Ut + (size_t)m*28*8192;
  trail_stage(Um + (size_t)pidx(j,row)*8192, Um + (size_t)pidx(j,b2)*8192, Ah, Al, Bh, Bl, t);
  __syncthreads();
  f32x4 acc[4];
  #pragma unroll
  for (int ni=0;ni<4;ni++) acc[ni] = (f32x4){0.f,0.f,0.f,0.f};
  trail_mfma(Ah, Al, Bh, Bl, acc, w, l15, lk);
  float* Cb = A + (size_t)m*D_*D_ + (size_t)(row*NB)*D_ + b2*NB;
  trail_rmw(Cb, acc, w, l15, lk);
}

// ---------------- trail2 (MFMA): upper(a,b) -= cols jb,jb+1 ----------------
__global__ __launch_bounds__(TPB) void k_trail2(float* __restrict__ A,
                                                const unsigned short* __restrict__ Ut,
                                                int jb, int W)
{
  int m, z; decode_mt(blockIdx.x, W, m, z);
  int base = jb + 2;
  int Tn = NT - base;
  int p = 0, zz = z;
  while (zz >= Tn - p){ zz -= Tn - p; p++; }
  int a2 = base + p, b2 = a2 + zz;
  int t = threadIdx.x, lane = t&63, w = t>>6, l15 = lane&15, lk = lane>>4;
  __shared__ unsigned short Ah[64][72], Al[64][72], Bh[64][72], Bl[64][72];
  const unsigned short* Um = Ut + (size_t)m*28*8192;
  f32x4 acc[4];
  #pragma unroll
  for (int ni=0;ni<4;ni++) acc[ni] = (f32x4){0.f,0.f,0.f,0.f};
  #pragma unroll
  for (int c=0;c<2;c++){
    int j = jb + c;
    __syncthreads();
    trail_stage(Um + (size_t)pidx(j,a2)*8192, Um + (size_t)pidx(j,b2)*8192, Ah, Al, Bh, Bl, t);
    __syncthreads();
    trail_mfma(Ah, Al, Bh, Bl, acc, w, l15, lk);
  }
  float* Cb = A + (size_t)m*D_*D_ + (size_t)(a2*NB)*D_ + b2*NB;
  trail_rmw(Cb, acc, w, l15, lk);
}

// ---------------- fused rform + forward solve + maha + logits ----------------
__global__ __launch_bounds__(TPB) void k_solvefin(const float* __restrict__ Qs,
                                                  const float* __restrict__ mu,
                                                  const float* __restrict__ A,
                                                  const float* __restrict__ invDT,
                                                  float* __restrict__ Z,
                                                  const int* __restrict__ qlen,
                                                  const float* __restrict__ lps,
                                                  float* __restrict__ out)
{
  int m, t0; decode_mt(blockIdx.x, 4, m, t0);
  int q0 = t0*NB;
  int b = m>>1, cls = m&1;
  int t = threadIdx.x, tr = t&15, tc = t>>4;
  __shared__ float Ta[64][68], Tb[64][68];
  const float* Am = A + (size_t)m*D_*D_;
  float* Zm = Z + (size_t)m*D_*Q_;
  const float* muv = mu + ((size_t)b*3 + cls)*D_;
  float cs[4] = {0.f,0.f,0.f,0.f};
  for (int j=0;j<NT;j++){
    float acc[4][4];
    {
      float4 mv = *(const float4*)&muv[j*NB + tr*4];
      #pragma unroll
      for (int v=0;v<4;v++){
        float4 qv = *(const float4*)&Qs[((size_t)b*Q_ + q0 + tc*4 + v)*D_ + j*NB + tr*4];
        acc[0][v] = mv.x - qv.x;
        acc[1][v] = mv.y - qv.y;
        acc[2][v] = mv.z - qv.z;
        acc[3][v] = mv.w - qv.w;
      }
    }
    for (int k=0;k<j;k++){
      stage_D(Am + (size_t)(k*NB)*D_ + j*NB, D_, Ta, t);
      { int r = t >> 2, seg = (t & 3)*16;
        const float4* s4 = (const float4*)(Zm + (size_t)(k*NB + r)*Q_ + q0 + seg);
        #pragma unroll
        for (int i=0;i<4;i++) *((float4*)&Tb[r][seg + i*4]) = s4[i];
      }
      __syncthreads();
      for (int kk=0;kk<64;kk++){
        float4 av = *((const float4*)&Ta[kk][tr*4]);
        float4 bv = *((const float4*)&Tb[kk][tc*4]);
        float a[4]={av.x,av.y,av.z,av.w}, bb2[4]={bv.x,bv.y,bv.z,bv.w};
        #pragma unroll
        for (int u=0;u<4;u++)
          #pragma unroll
          for (int v=0;v<4;v++) acc[u][v] = fmaf(-a[u], bb2[v], acc[u][v]);
      }
      __syncthreads();
    }
    #pragma unroll
    for (int u=0;u<4;u++)
      #pragma unroll
      for (int v=0;v<4;v++) Tb[tr*4+u][tc*4+v] = acc[u][v];
    stage_D(invDT + ((size_t)m*8 + j)*4096, 64, Ta, t);
    __syncthreads();
    float o4[4][4] = {};
    for (int kk=0;kk<64;kk++){
      float4 av = *((const float4*)&Ta[kk][tr*4]);
      float4 bv = *((const float4*)&Tb[kk][tc*4]);
      float a[4]={av.x,av.y,av.z,av.w}, bb2[4]={bv.x,bv.y,bv.z,bv.w};
      #pragma unroll
      for (int u=0;u<4;u++)
        #pragma unroll
        for (int v=0;v<4;v++) o4[u][v] = fmaf(a[u], bb2[v], o4[u][v]);
    }
    if (j < NT-1){
      #pragma unroll
      for (int u=0;u<4;u++){
        float4 o = make_float4(o4[u][0], o4[u][1], o4[u][2], o4[u][3]);
        *((float4*)(Zm + (size_t)(j*NB + tr*4+u)*Q_ + q0 + tc*4)) = o;
      }
    }
    #pragma unroll
    for (int u=0;u<4;u++)
      #pragma unroll
      for (int v=0;v<4;v++) cs[v] = fmaf(o4[u][v], o4[u][v], cs[v]);
    __syncthreads();
  }
  float* red = &Ta[0][0];
  #pragma unroll
  for (int v=0;v<4;v++) red[(tc*4+v)*16 + tr] = cs[v];
  __syncthreads();
  if (t < 64){
    float s = 0.f;
    #pragma unroll
    for (int i=0;i<16;i++) s += red[t*16 + i];
    int q = q0 + t;
    float valid = (q < qlen[b]) ? 1.f : 0.f;
    float s2 = expf(2.f*lps[0]);
    out[((size_t)b*Q_ + q)*2 + cls] = -s2*s*valid;
  }
}

extern "C" void kernel_launch(void* const* d_in, const int* in_sizes, int n_in,
                              void* d_out, int out_size, void* d_ws, size_t ws_size,
                              hipStream_t stream) {
  (void)in_sizes; (void)n_in; (void)out_size;
  const float* X   = (const float*)d_in[0];
  const int*   lab = (const int*)d_in[1];
  const float* Qs  = (const float*)d_in[2];
  const int*   sl  = (const int*)d_in[3];
  const int*   ql  = (const int*)d_in[4];
  const float* lps = (const float*)d_in[5];
  float* out = (float*)d_out;

  float* A  = (float*)d_ws;                          // [512,512,512] f32
  float* Z  = A + (size_t)NM_*D_*D_;                 // [512,512,256] f32
  unsigned short* Xvh = (unsigned short*)Z;          // overlays Z (gram phase only)
  unsigned short* Xvl = Xvh + (size_t)B_*D_*S_;
  unsigned short* Ut  = (unsigned short*)Z;          // overlays Z (chol phase only): [512][28][8192]
  float* invDT = Z + (size_t)NM_*D_*Q_;              // [512,8,64,64] f32 (transposed)
  float* mu   = invDT + (size_t)NM_*8*64*64;         // [256,3,512]
  float* cnt  = mu + (size_t)B_*3*D_;                // [256,2]
  unsigned int* wpbits = (unsigned int*)(cnt + B_*2);// [256,16]
  size_t need = (size_t)((char*)(wpbits + B_*16) - (char*)d_ws);
  if (ws_size < need) return;

  k_stats<<<dim3(B_), dim3(1024), 0, stream>>>(X, lab, sl, mu, cnt, wpbits);
  k_prep<<<dim3(64, B_), dim3(TPB), 0, stream>>>(X, sl, Xvh, Xvl);
  k_gram<<<dim3(2560), dim3(TPB), 0, stream>>>(Xvh, Xvl, wpbits, mu, cnt, sl, A);

  // lazy two-column Cholesky with MFMA trail (f16T panels live in the Z region)
  for (int j=0; j<NT; j+=2){
    k_diag<<<dim3(NM_), dim3(TPB), 0, stream>>>(A, invDT, j);
    int nb0 = NT-1-j;
    if (nb0 > 0){
      k_panel<<<dim3(NM_*nb0), dim3(TPB), 0, stream>>>(A, invDT, Ut, j, nb0);
      int wr = NT - (j+1);
      k_trailrow<<<dim3(NM_*wr), dim3(TPB), 0, stream>>>(A, Ut, j, j+1, wr);
      k_diag<<<dim3(NM_), dim3(TPB), 0, stream>>>(A, invDT, j+1);
      int nb1 = NT-1-(j+1);
      if (nb1 > 0){
        k_panel<<<dim3(NM_*nb1), dim3(TPB), 0, stream>>>(A, invDT, Ut, j+1, nb1);
        int Tn = NT - (j+2);
        int np = Tn*(Tn+1)/2;
        if (np > 0) k_trail2<<<dim3(NM_*np), dim3(TPB), 0, stream>>>(A, Ut, j, np);
      }
    }
  }

  k_solvefin<<<dim3(NM_*4), dim3(TPB), 0, stream>>>(Qs, mu, A, invDT, Z, ql, lps, out);
}

// Round 12
// 2391.299 us; speedup vs baseline: 1.1211x; 1.0742x over previous
//
#include <hip/hip_runtime.h>
#include <hip/hip_bf16.h>

#define TPB 256
constexpr int B_ = 256, S_ = 512, D_ = 512, Q_ = 256, NM_ = 512;
constexpr int NB = 64, NT = 8;

typedef _Float16 f16x8 __attribute__((ext_vector_type(8)));
typedef float f32x4 __attribute__((ext_vector_type(4)));

__device__ __forceinline__ int pidx(int j, int a){ return j*(15-j)/2 + (a-j-1); } // j<a, 28 tiles

// XCD-co-locating decode: x=bid&7 -> XCD; per XCD: tasks fastest, then cls, then group.
__device__ __forceinline__ void decode_mt(int bid, int W, int& m, int& t){
  int x = bid & 7, r = bid >> 3;
  t = r % W; int u = r / W;
  m = (((u >> 1)*8 + x) << 1) | (u & 1);
}

// direct row-major 64x64 stage into pitch-68 LDS (256 threads)
__device__ __forceinline__ void stage_D(const float* __restrict__ src, size_t ld,
                                        float (*dst)[68], int t)
{
  int r = t >> 2, seg = (t & 3) * 16;
  const float4* s4 = (const float4*)(src + (size_t)r*ld + seg);
  #pragma unroll
  for (int i=0;i<4;i++) *((float4*)&dst[r][seg + i*4]) = s4[i];
}

// acc[u][v] += sum_kk Aop[kk][tr*4+u] * Bop[kk][tc*4+v]
__device__ __forceinline__ void mm_acc68(const float (*Aop)[68], const float (*Bop)[68],
                                         float acc[4][4], int tr, int tc)
{
  for (int kk=0;kk<64;kk++){
    float4 av = *((const float4*)&Aop[kk][tr*4]);
    float4 bv = *((const float4*)&Bop[kk][tc*4]);
    float a[4]={av.x,av.y,av.z,av.w}, b2[4]={bv.x,bv.y,bv.z,bv.w};
    #pragma unroll
    for (int u=0;u<4;u++)
      #pragma unroll
      for (int v=0;v<4;v++) acc[u][v] = fmaf(a[u], b2[v], acc[u][v]);
  }
}

// ---------------- prep (fused stats): transpose X -> f16 hi/lo [B][D][S], masked;
// also computes mu (3 means), cnt, wpbits. One block per (b, d-tile), loops 8 s-tiles.
__global__ __launch_bounds__(TPB) void k_prep(const float* __restrict__ X,
                                              const int* __restrict__ labels,
                                              const int* __restrict__ slen,
                                              unsigned short* __restrict__ Xvh,
                                              unsigned short* __restrict__ Xvl,
                                              float* __restrict__ mu,
                                              float* __restrict__ cnt,
                                              unsigned int* __restrict__ wpbits)
{
  int b = blockIdx.y, dz = blockIdx.x;
  int d0 = dz*64;
  int t = threadIdx.x;
  __shared__ float Tl[64][65];
  __shared__ int lab[S_];
  __shared__ float red[TPB];
  int L = slen[b];
  for (int s = t; s < S_; s += TPB){
    int lb = labels[b*S_ + s];
    lab[s] = (s < L) ? lb : -1;
  }
  __syncthreads();
  if (dz == 0 && t < 16){
    unsigned int wword = 0;
    for (int i2=0;i2<32;i2++) if (lab[t*32+i2]==1) wword |= (1u<<i2);
    wpbits[b*16+t] = wword;
  }
  int cpi=0, cni=0;
  for (int s=t; s<S_; s+=TPB){ cpi += (lab[s]==1); cni += (lab[s]==0); }
  red[t] = (float)cpi; __syncthreads();
  for (int o=TPB/2;o>0;o>>=1){ if(t<o) red[t]+=red[t+o]; __syncthreads(); }
  float cp = red[0]; __syncthreads();
  red[t] = (float)cni; __syncthreads();
  for (int o=TPB/2;o>0;o>>=1){ if(t<o) red[t]+=red[t+o]; __syncthreads(); }
  float cn = red[0];
  if (dz==0 && t==0){ cnt[b*2+0]=cn; cnt[b*2+1]=cp; }
  __syncthreads();

  int dr = t>>2, sc = (t&3)*16;
  float accp = 0.f, accn = 0.f;
  for (int sz=0; sz<8; sz++){
    int s0 = sz*64;
    const float* src = X + ((size_t)b*S_ + s0)*D_ + d0;
    { int r = t>>2, seg = (t&3)*16;
      const float4* s4 = (const float4*)(src + (size_t)r*D_ + seg);
      #pragma unroll
      for (int i=0;i<4;i++){ float4 v = s4[i];
        Tl[seg+i*4+0][r]=v.x; Tl[seg+i*4+1][r]=v.y; Tl[seg+i*4+2][r]=v.z; Tl[seg+i*4+3][r]=v.w; } }
    __syncthreads();
    union U16 { unsigned short u[8]; uint4 v; };
    U16 H[2], Lo[2];
    #pragma unroll
    for (int g=0; g<2; g++)
      #pragma unroll
      for (int i=0;i<8;i++){
        int si = sc + g*8 + i;
        float x = (s0+si < L) ? Tl[dr][si] : 0.f;
        _Float16 hh = (_Float16)x;
        float lo = x - (float)hh;
        H[g].u[i]  = __builtin_bit_cast(unsigned short, hh);
        Lo[g].u[i] = __builtin_bit_cast(unsigned short, (_Float16)lo);
      }
    size_t o = ((size_t)b*D_ + d0+dr)*S_ + s0 + sc;
    *(uint4*)(Xvh+o)   = H[0].v;  *(uint4*)(Xvh+o+8) = H[1].v;
    *(uint4*)(Xvl+o)   = Lo[0].v; *(uint4*)(Xvl+o+8) = Lo[1].v;
    // masked per-d partial sums over this thread's 16 s values
    #pragma unroll
    for (int i=0;i<16;i++){
      int si = sc + i;
      int e = lab[s0+si];
      float x = Tl[dr][si];
      accp += (e==1) ? x : 0.f;
      accn += (e==0) ? x : 0.f;
    }
    __syncthreads();
  }
  // 4-lane group reduce (threads sharing dr are 4 consecutive lanes)
  accp += __shfl_xor(accp, 1, 64);
  accp += __shfl_xor(accp, 2, 64);
  accn += __shfl_xor(accn, 1, 64);
  accn += __shfl_xor(accn, 2, 64);
  if ((t&3)==0){
    int d = d0 + dr;
    float stv = (float)L;
    float* mb = mu + (size_t)b*3*D_;
    mb[0*D_ + d] = accn/cn;
    mb[1*D_ + d] = accp/cp;
    mb[2*D_ + d] = (accn+accp)/stv;
  }
}

// ---------------- MFMA Gram -> A matrices (upper 128-tiles incl. diagonal) ----------------
__global__ __launch_bounds__(TPB,2) void k_gram(const unsigned short* __restrict__ Xvh,
                                                const unsigned short* __restrict__ Xvl,
                                                const unsigned int* __restrict__ wpbits,
                                                const float* __restrict__ mu,
                                                const float* __restrict__ cnt,
                                                const int* __restrict__ slen,
                                                float* __restrict__ A)
{
  __shared__ unsigned short sAvh[128][32], sAvl[128][32], sAph[128][32], sApl[128][32],
                            sBvh[128][32], sBvl[128][32];
  int id = blockIdx.x;
  int g = id>>3;
  int b = (g/10)*8 + (id&7);
  int z = g%10;
  int ti=0; while (z >= 4-ti){ z -= 4-ti; ti++; } int tj = ti + z;
  int i0 = ti*128, j0 = tj*128;
  int t = threadIdx.x, lane = t&63, w = t>>6;
  int wr = w>>1, wc = w&1, l15 = lane&15;

  f32x4 acc_t[4][4], acc_p[4][4];
  f32x4 z4 = {0.f,0.f,0.f,0.f};
  #pragma unroll
  for (int mf=0;mf<4;mf++)
    #pragma unroll
    for (int nf=0;nf<4;nf++){ acc_t[mf][nf]=z4; acc_p[mf][nf]=z4; }

  const size_t baseA = ((size_t)b*D_ + i0)*S_;
  const size_t baseB = ((size_t)b*D_ + j0)*S_;
  int phx = (lane>>4) ^ ((l15>>1)&3);

  for (int ks=0; ks<16; ks++){
    int s0 = ks*32;
    unsigned int wpw = wpbits[b*16 + ks];
    __syncthreads();
    #pragma unroll
    for (int h=0; h<2; h++){
      int ci = t + h*256;
      int row = ci>>2, cpos = ci&3;
      int ph = cpos ^ ((row>>1)&3);
      size_t ga = baseA + (size_t)row*S_ + s0 + cpos*8;
      size_t gb = baseB + (size_t)row*S_ + s0 + cpos*8;
      uint4 vh = *(const uint4*)(Xvh+ga);
      uint4 vl = *(const uint4*)(Xvl+ga);
      uint4 bh = *(const uint4*)(Xvh+gb);
      uint4 bl = *(const uint4*)(Xvl+gb);
      unsigned int m8 = (wpw >> (cpos*8)) & 0xFFu;
      uint4 mk;
      mk.x = ((m8&1u)?0xFFFFu:0u)  | ((m8&2u)?0xFFFF0000u:0u);
      mk.y = ((m8&4u)?0xFFFFu:0u)  | ((m8&8u)?0xFFFF0000u:0u);
      mk.z = ((m8&16u)?0xFFFFu:0u) | ((m8&32u)?0xFFFF0000u:0u);
      mk.w = ((m8&64u)?0xFFFFu:0u) | ((m8&128u)?0xFFFF0000u:0u);
      uint4 p4, q4;
      p4.x = vh.x&mk.x; p4.y = vh.y&mk.y; p4.z = vh.z&mk.z; p4.w = vh.w&mk.w;
      q4.x = vl.x&mk.x; q4.y = vl.y&mk.y; q4.z = vl.z&mk.z; q4.w = vl.w&mk.w;
      *(uint4*)&sAvh[row][ph*8] = vh;
      *(uint4*)&sAvl[row][ph*8] = vl;
      *(uint4*)&sAph[row][ph*8] = p4;
      *(uint4*)&sApl[row][ph*8] = q4;
      *(uint4*)&sBvh[row][ph*8] = bh;
      *(uint4*)&sBvl[row][ph*8] = bl;
    }
    __syncthreads();
    f16x8 Avh[4], Avl[4], Aph[4], Apl[4];
    #pragma unroll
    for (int mf=0;mf<4;mf++){
      int r = wr*64 + mf*16 + l15;
      Avh[mf] = __builtin_bit_cast(f16x8, *(const uint4*)&sAvh[r][phx*8]);
      Avl[mf] = __builtin_bit_cast(f16x8, *(const uint4*)&sAvl[r][phx*8]);
      Aph[mf] = __builtin_bit_cast(f16x8, *(const uint4*)&sAph[r][phx*8]);
      Apl[mf] = __builtin_bit_cast(f16x8, *(const uint4*)&sApl[r][phx*8]);
    }
    #pragma unroll
    for (int nf=0;nf<4;nf++){
      int r = wc*64 + nf*16 + l15;
      f16x8 Bh = __builtin_bit_cast(f16x8, *(const uint4*)&sBvh[r][phx*8]);
      f16x8 Bl = __builtin_bit_cast(f16x8, *(const uint4*)&sBvl[r][phx*8]);
      #pragma unroll
      for (int mf=0;mf<4;mf++){
        acc_t[mf][nf] = __builtin_amdgcn_mfma_f32_16x16x32_f16(Avh[mf], Bh, acc_t[mf][nf],0,0,0);
        acc_t[mf][nf] = __builtin_amdgcn_mfma_f32_16x16x32_f16(Avh[mf], Bl, acc_t[mf][nf],0,0,0);
        acc_t[mf][nf] = __builtin_amdgcn_mfma_f32_16x16x32_f16(Avl[mf], Bh, acc_t[mf][nf],0,0,0);
        acc_p[mf][nf] = __builtin_amdgcn_mfma_f32_16x16x32_f16(Aph[mf], Bh, acc_p[mf][nf],0,0,0);
        acc_p[mf][nf] = __builtin_amdgcn_mfma_f32_16x16x32_f16(Aph[mf], Bl, acc_p[mf][nf],0,0,0);
        acc_p[mf][nf] = __builtin_amdgcn_mfma_f32_16x16x32_f16(Apl[mf], Bh, acc_p[mf][nf],0,0,0);
      }
    }
  }
  float cn = cnt[b*2+0], cp = cnt[b*2+1];
  float stv = (float)slen[b];
  float kn = 0.1f/(cn-1.f), kp = 0.1f/(cp-1.f), kt = 0.9f/(stv-1.f);
  float rn = 0.1f*cn/(cn-1.f), rp = 0.1f*cp/(cp-1.f), rt = 0.9f*stv/(stv-1.f);
  const float* mb = mu + (size_t)b*3*D_;
  float* A0 = A + (size_t)(b*2+0)*D_*D_;
  float* A1 = A + (size_t)(b*2+1)*D_*D_;
  int rbase = i0 + wr*64 + (lane>>4)*4;
  int cbase = j0 + wc*64 + l15;
  #pragma unroll
  for (int mf=0;mf<4;mf++){
    #pragma unroll
    for (int i=0;i<4;i++){
      int r = rbase + mf*16 + i;
      float mnr = mb[r], mpr = mb[D_+r], mtr = mb[2*D_+r];
      #pragma unroll
      for (int nf=0;nf<4;nf++){
        int c = cbase + nf*16;
        float mnc = mb[c], mpc = mb[D_+c], mtc = mb[2*D_+c];
        float gp = acc_p[mf][nf][i];
        float gt = acc_t[mf][nf][i];
        float gn = gt - gp;
        float diag = (r==c)?0.1f:0.f;
        A0[(size_t)r*D_ + c] = kn*gn + kt*gt - rn*mnr*mnc - rt*mtr*mtc + diag;
        A1[(size_t)r*D_ + c] = kp*gp + kt*gt - rp*mpr*mpc - rt*mtr*mtc + diag;
      }
    }
  }
}

// ---------------- diag block Cholesky + triangular inverse (transposed out) ----------------
__global__ __launch_bounds__(TPB) void k_diag(float* __restrict__ A,
                                              float* __restrict__ invDT, int j)
{
  int m, t0; decode_mt(blockIdx.x, 1, m, t0); (void)t0;
  int t = threadIdx.x;
  __shared__ float Ld[64][65];
  __shared__ float Iv[64][65];
  float* Ab = A + (size_t)m*D_*D_ + (size_t)(j*NB)*D_ + j*NB;
  for (int l=t; l<4096; l+=TPB){ int r=l>>6, c=l&63; Ld[r][c] = Ab[(size_t)r*D_ + c]; Iv[r][c] = 0.f; }
  __syncthreads();
  for (int k=0;k<64;k++){
    if (t==0) Ld[k][k] = sqrtf(Ld[k][k]);
    __syncthreads();
    if (t>k && t<64) Ld[t][k] /= Ld[k][k];
    __syncthreads();
    for (int l=t; l<4096; l+=TPB){
      int r=l>>6, c=l&63;
      if (r>k && c>k) Ld[r][c] = fmaf(-Ld[r][k], Ld[c][k], Ld[r][c]);
    }
    __syncthreads();
  }
  if (t < 64){
    int c = t;
    Iv[c][c] = 1.f/Ld[c][c];
    for (int r=c+1;r<64;r++){
      float s = 0.f;
      for (int k2=c;k2<r;k2++) s += Ld[r][k2]*Iv[k2][c];
      Iv[r][c] = -s/Ld[r][r];
    }
  }
  __syncthreads();
  float* Ib = invDT + ((size_t)m*8 + j)*4096;
  for (int l=t; l<4096; l+=TPB){ Ib[l] = Iv[l&63][l>>6]; }
}

// ---------------- panel: upper(j,ib) <- invD * upper(j,ib); emit f16T hi/lo ----------------
__global__ __launch_bounds__(TPB) void k_panel(float* __restrict__ A,
                                               const float* __restrict__ invDT,
                                               unsigned short* __restrict__ Ut,
                                               int j, int W)
{
  int m, ti; decode_mt(blockIdx.x, W, m, ti);
  int ib = j + 1 + ti;
  int t = threadIdx.x, tr = t&15, tc = t>>4;
  __shared__ float Ta[64][68], Tb[64][68];
  float* U = A + (size_t)m*D_*D_ + (size_t)(j*NB)*D_ + ib*NB;
  stage_D(invDT + ((size_t)m*8 + j)*4096, 64, Ta, t);
  stage_D(U, D_, Tb, t);
  __syncthreads();
  float acc[4][4] = {};
  mm_acc68(Ta, Tb, acc, tr, tc);
  #pragma unroll
  for (int u=0;u<4;u++){
    float4 o = make_float4(acc[u][0],acc[u][1],acc[u][2],acc[u][3]);
    *((float4*)(U + (size_t)(tr*4+u)*D_ + tc*4)) = o;
  }
  __syncthreads();
  unsigned short* shh = (unsigned short*)Ta;
  unsigned short* shl = (unsigned short*)Tb;
  #pragma unroll
  for (int u=0;u<4;u++)
    #pragma unroll
    for (int v=0;v<4;v++){
      float val = acc[u][v];                  // P[x=tr*4+u][y=tc*4+v]
      _Float16 h = (_Float16)val;
      float lo = val - (float)h;
      shh[(tc*4+v)*72 + tr*4+u] = __builtin_bit_cast(unsigned short, h);
      shl[(tc*4+v)*72 + tr*4+u] = __builtin_bit_cast(unsigned short, (_Float16)lo);
    }
  __syncthreads();
  unsigned short* Ub = Ut + ((size_t)m*28 + pidx(j, ib)) * 8192;
  { int r = t>>2, cs = (t&3)*16;
    *(uint4*)(Ub + r*64 + cs)          = *(uint4*)&shh[r*72 + cs];
    *(uint4*)(Ub + r*64 + cs + 8)      = *(uint4*)&shh[r*72 + cs + 8];
    *(uint4*)(Ub + 4096 + r*64 + cs)   = *(uint4*)&shl[r*72 + cs];
    *(uint4*)(Ub + 4096 + r*64 + cs+8) = *(uint4*)&shl[r*72 + cs + 8];
  }
}

// ---------------- MFMA trail helpers ----------------
__device__ __forceinline__ void trail_stage(const unsigned short* __restrict__ Ua,
                                            const unsigned short* __restrict__ Ub,
                                            unsigned short (*Ah)[72], unsigned short (*Al)[72],
                                            unsigned short (*Bh)[72], unsigned short (*Bl)[72],
                                            int t)
{
  int r = t>>2, cs = (t&3)*16;
  *(uint4*)&Ah[r][cs]   = *(const uint4*)(Ua + r*64 + cs);
  *(uint4*)&Ah[r][cs+8] = *(const uint4*)(Ua + r*64 + cs + 8);
  *(uint4*)&Al[r][cs]   = *(const uint4*)(Ua + 4096 + r*64 + cs);
  *(uint4*)&Al[r][cs+8] = *(const uint4*)(Ua + 4096 + r*64 + cs + 8);
  *(uint4*)&Bh[r][cs]   = *(const uint4*)(Ub + r*64 + cs);
  *(uint4*)&Bh[r][cs+8] = *(const uint4*)(Ub + r*64 + cs + 8);
  *(uint4*)&Bl[r][cs]   = *(const uint4*)(Ub + 4096 + r*64 + cs);
  *(uint4*)&Bl[r][cs+8] = *(const uint4*)(Ub + 4096 + r*64 + cs + 8);
}

__device__ __forceinline__ void trail_mfma(const unsigned short (*Ah)[72], const unsigned short (*Al)[72],
                                           const unsigned short (*Bh)[72], const unsigned short (*Bl)[72],
                                           f32x4 acc[4], int w, int l15, int lk)
{
  #pragma unroll
  for (int s=0;s<2;s++){
    f16x8 Afh = __builtin_bit_cast(f16x8, *(const uint4*)&Ah[w*16 + l15][s*32 + lk*8]);
    f16x8 Afl = __builtin_bit_cast(f16x8, *(const uint4*)&Al[w*16 + l15][s*32 + lk*8]);
    #pragma unroll
    for (int ni=0;ni<4;ni++){
      f16x8 Bfh = __builtin_bit_cast(f16x8, *(const uint4*)&Bh[ni*16 + l15][s*32 + lk*8]);
      f16x8 Bfl = __builtin_bit_cast(f16x8, *(const uint4*)&Bl[ni*16 + l15][s*32 + lk*8]);
      acc[ni] = __builtin_amdgcn_mfma_f32_16x16x32_f16(Afh, Bfh, acc[ni],0,0,0);
      acc[ni] = __builtin_amdgcn_mfma_f32_16x16x32_f16(Afh, Bfl, acc[ni],0,0,0);
      acc[ni] = __builtin_amdgcn_mfma_f32_16x16x32_f16(Afl, Bfh, acc[ni],0,0,0);
    }
  }
}

__device__ __forceinline__ void trail_rmw(float* __restrict__ Cb, const f32x4 acc[4],
                                          int w, int l15, int lk)
{
  #pragma unroll
  for (int ni=0;ni<4;ni++)
    #pragma unroll
    for (int i=0;i<4;i++){
      int r = w*16 + lk*4 + i, cc = ni*16 + l15;
      float* pC = Cb + (size_t)r*D_ + cc;
      *pC -= acc[ni][i];
    }
}

// ---------------- trailrow (MFMA): upper(row,b) -= U(j,row)^T U(j,b) ----------------
__global__ __launch_bounds__(TPB) void k_trailrow(float* __restrict__ A,
                                                  const unsigned short* __restrict__ Ut,
                                                  int j, int row, int W)
{
  int m, z; decode_mt(blockIdx.x, W, m, z);
  int b2 = row + z;
  int t = threadIdx.x, lane = t&63, w = t>>6, l15 = lane&15, lk = lane>>4;
  __shared__ unsigned short Ah[64][72], Al[64][72], Bh[64][72], Bl[64][72];
  const unsigned short* Um = Ut + (size_t)m*28*8192;
  trail_stage(Um + (size_t)pidx(j,row)*8192, Um + (size_t)pidx(j,b2)*8192, Ah, Al, Bh, Bl, t);
  __syncthreads();
  f32x4 acc[4];
  #pragma unroll
  for (int ni=0;ni<4;ni++) acc[ni] = (f32x4){0.f,0.f,0.f,0.f};
  trail_mfma(Ah, Al, Bh, Bl, acc, w, l15, lk);
  float* Cb = A + (size_t)m*D_*D_ + (size_t)(row*NB)*D_ + b2*NB;
  trail_rmw(Cb, acc, w, l15, lk);
}

// ---------------- trail2 (MFMA): upper(a,b) -= cols jb,jb+1 ----------------
__global__ __launch_bounds__(TPB) void k_trail2(float* __restrict__ A,
                                                const unsigned short* __restrict__ Ut,
                                                int jb, int W)
{
  int m, z; decode_mt(blockIdx.x, W, m, z);
  int base = jb + 2;
  int Tn = NT - base;
  int p = 0, zz = z;
  while (zz >= Tn - p){ zz -= Tn - p; p++; }
  int a2 = base + p, b2 = a2 + zz;
  int t = threadIdx.x, lane = t&63, w = t>>6, l15 = lane&15, lk = lane>>4;
  __shared__ unsigned short Ah[64][72], Al[64][72], Bh[64][72], Bl[64][72];
  const unsigned short* Um = Ut + (size_t)m*28*8192;
  f32x4 acc[4];
  #pragma unroll
  for (int ni=0;ni<4;ni++) acc[ni] = (f32x4){0.f,0.f,0.f,0.f};
  #pragma unroll
  for (int c=0;c<2;c++){
    int j = jb + c;
    __syncthreads();
    trail_stage(Um + (size_t)pidx(j,a2)*8192, Um + (size_t)pidx(j,b2)*8192, Ah, Al, Bh, Bl, t);
    __syncthreads();
    trail_mfma(Ah, Al, Bh, Bl, acc, w, l15, lk);
  }
  float* Cb = A + (size_t)m*D_*D_ + (size_t)(a2*NB)*D_ + b2*NB;
  trail_rmw(Cb, acc, w, l15, lk);
}

// ---------------- fused rform + forward solve + maha + logits ----------------
__global__ __launch_bounds__(TPB) void k_solvefin(const float* __restrict__ Qs,
                                                  const float* __restrict__ mu,
                                                  const float* __restrict__ A,
                                                  const float* __restrict__ invDT,
                                                  float* __restrict__ Z,
                                                  const int* __restrict__ qlen,
                                                  const float* __restrict__ lps,
                                                  float* __restrict__ out)
{
  int m, t0; decode_mt(blockIdx.x, 4, m, t0);
  int q0 = t0*NB;
  int b = m>>1, cls = m&1;
  int t = threadIdx.x, tr = t&15, tc = t>>4;
  __shared__ float Ta[64][68], Tb[64][68];
  const float* Am = A + (size_t)m*D_*D_;
  float* Zm = Z + (size_t)m*D_*Q_;
  const float* muv = mu + ((size_t)b*3 + cls)*D_;
  float cs[4] = {0.f,0.f,0.f,0.f};
  for (int j=0;j<NT;j++){
    float acc[4][4];
    {
      float4 mv = *(const float4*)&muv[j*NB + tr*4];
      #pragma unroll
      for (int v=0;v<4;v++){
        float4 qv = *(const float4*)&Qs[((size_t)b*Q_ + q0 + tc*4 + v)*D_ + j*NB + tr*4];
        acc[0][v] = mv.x - qv.x;
        acc[1][v] = mv.y - qv.y;
        acc[2][v] = mv.z - qv.z;
        acc[3][v] = mv.w - qv.w;
      }
    }
    for (int k=0;k<j;k++){
      stage_D(Am + (size_t)(k*NB)*D_ + j*NB, D_, Ta, t);
      { int r = t >> 2, seg = (t & 3)*16;
        const float4* s4 = (const float4*)(Zm + (size_t)(k*NB + r)*Q_ + q0 + seg);
        #pragma unroll
        for (int i=0;i<4;i++) *((float4*)&Tb[r][seg + i*4]) = s4[i];
      }
      __syncthreads();
      for (int kk=0;kk<64;kk++){
        float4 av = *((const float4*)&Ta[kk][tr*4]);
        float4 bv = *((const float4*)&Tb[kk][tc*4]);
        float a[4]={av.x,av.y,av.z,av.w}, bb2[4]={bv.x,bv.y,bv.z,bv.w};
        #pragma unroll
        for (int u=0;u<4;u++)
          #pragma unroll
          for (int v=0;v<4;v++) acc[u][v] = fmaf(-a[u], bb2[v], acc[u][v]);
      }
      __syncthreads();
    }
    // S -> Tb with XOR granule swizzle (kills 8-way scatter conflict)
    #pragma unroll
    for (int u=0;u<4;u++){
      int cb = (tc*4) ^ ((tr&7)<<2);
      *((float4*)&Tb[tr*4+u][cb]) = make_float4(acc[u][0],acc[u][1],acc[u][2],acc[u][3]);
    }
    stage_D(invDT + ((size_t)m*8 + j)*4096, 64, Ta, t);
    __syncthreads();
    float o4[4][4] = {};
    for (int kk=0;kk<64;kk++){
      float4 av = *((const float4*)&Ta[kk][tr*4]);
      float4 bv = *((const float4*)&Tb[kk][(tc*4) ^ (((kk>>2)&7)<<2)]);
      float a[4]={av.x,av.y,av.z,av.w}, bb2[4]={bv.x,bv.y,bv.z,bv.w};
      #pragma unroll
      for (int u=0;u<4;u++)
        #pragma unroll
        for (int v=0;v<4;v++) o4[u][v] = fmaf(a[u], bb2[v], o4[u][v]);
    }
    if (j < NT-1){
      #pragma unroll
      for (int u=0;u<4;u++){
        float4 o = make_float4(o4[u][0], o4[u][1], o4[u][2], o4[u][3]);
        *((float4*)(Zm + (size_t)(j*NB + tr*4+u)*Q_ + q0 + tc*4)) = o;
      }
    }
    #pragma unroll
    for (int u=0;u<4;u++)
      #pragma unroll
      for (int v=0;v<4;v++) cs[v] = fmaf(o4[u][v], o4[u][v], cs[v]);
    __syncthreads();
  }
  float* red = &Ta[0][0];
  #pragma unroll
  for (int v=0;v<4;v++) red[(tc*4+v)*16 + tr] = cs[v];
  __syncthreads();
  if (t < 64){
    float s = 0.f;
    #pragma unroll
    for (int i=0;i<16;i++) s += red[t*16 + i];
    int q = q0 + t;
    float valid = (q < qlen[b]) ? 1.f : 0.f;
    float s2 = expf(2.f*lps[0]);
    out[((size_t)b*Q_ + q)*2 + cls] = -s2*s*valid;
  }
}

extern "C" void kernel_launch(void* const* d_in, const int* in_sizes, int n_in,
                              void* d_out, int out_size, void* d_ws, size_t ws_size,
                              hipStream_t stream) {
  (void)in_sizes; (void)n_in; (void)out_size;
  const float* X   = (const float*)d_in[0];
  const int*   lab = (const int*)d_in[1];
  const float* Qs  = (const float*)d_in[2];
  const int*   sl  = (const int*)d_in[3];
  const int*   ql  = (const int*)d_in[4];
  const float* lps = (const float*)d_in[5];
  float* out = (float*)d_out;

  float* A  = (float*)d_ws;                          // [512,512,512] f32
  float* Z  = A + (size_t)NM_*D_*D_;                 // [512,512,256] f32
  unsigned short* Xvh = (unsigned short*)Z;          // overlays Z (gram phase only)
  unsigned short* Xvl = Xvh + (size_t)B_*D_*S_;
  unsigned short* Ut  = (unsigned short*)Z;          // overlays Z (chol phase only): [512][28][8192]
  float* invDT = Z + (size_t)NM_*D_*Q_;              // [512,8,64,64] f32 (transposed)
  float* mu   = invDT + (size_t)NM_*8*64*64;         // [256,3,512]
  float* cnt  = mu + (size_t)B_*3*D_;                // [256,2]
  unsigned int* wpbits = (unsigned int*)(cnt + B_*2);// [256,16]
  size_t need = (size_t)((char*)(wpbits + B_*16) - (char*)d_ws);
  if (ws_size < need) return;

  k_prep<<<dim3(8, B_), dim3(TPB), 0, stream>>>(X, lab, sl, Xvh, Xvl, mu, cnt, wpbits);
  k_gram<<<dim3(2560), dim3(TPB), 0, stream>>>(Xvh, Xvl, wpbits, mu, cnt, sl, A);

  // lazy two-column Cholesky with MFMA trail (f16T panels live in the Z region)
  for (int j=0; j<NT; j+=2){
    k_diag<<<dim3(NM_), dim3(TPB), 0, stream>>>(A, invDT, j);
    int nb0 = NT-1-j;
    if (nb0 > 0){
      k_panel<<<dim3(NM_*nb0), dim3(TPB), 0, stream>>>(A, invDT, Ut, j, nb0);
      int wr = NT - (j+1);
      k_trailrow<<<dim3(NM_*wr), dim3(TPB), 0, stream>>>(A, Ut, j, j+1, wr);
      k_diag<<<dim3(NM_), dim3(TPB), 0, stream>>>(A, invDT, j+1);
      int nb1 = NT-1-(j+1);
      if (nb1 > 0){
        k_panel<<<dim3(NM_*nb1), dim3(TPB), 0, stream>>>(A, invDT, Ut, j+1, nb1);
        int Tn = NT - (j+2);
        int np = Tn*(Tn+1)/2;
        if (np > 0) k_trail2<<<dim3(NM_*np), dim3(TPB), 0, stream>>>(A, Ut, j, np);
      }
    }
  }

  k_solvefin<<<dim3(NM_*4), dim3(TPB), 0, stream>>>(Qs, mu, A, invDT, Z, ql, lps, out);
}